// Round 1
// baseline (176.886 us; speedup 1.0000x reference)
//
#include <hip/hip_runtime.h>

// HGNN forward, MI355X. fp32 throughout.
// Algebra: masked-mean (sums ALL neighbors, scales by 1/cnt_nonzero) commutes
// with the linear maps, so we average embeddings first, then do one pair of
// 64x64 matmuls per row. Wave-per-row, lane j = output element j, W rows in
// VGPRs, x broadcast via v_readlane.

__device__ __forceinline__ int rfl(int v) { return __builtin_amdgcn_readfirstlane(v); }

__device__ __forceinline__ float bcastf(float v, int l) {
    return __int_as_float(__builtin_amdgcn_readlane(__float_as_int(v), l));
}

__device__ __forceinline__ float leakyf(float x) {
    return x >= 0.f ? x : 0.2f * x;
}

__device__ __forceinline__ void load_wrow(float (&w)[64], const float* __restrict__ W, int lane) {
    const float4* p = reinterpret_cast<const float4*>(W) + lane * 16;
#pragma unroll
    for (int t = 0; t < 16; ++t) {
        float4 v = p[t];
        w[4*t+0] = v.x; w[4*t+1] = v.y; w[4*t+2] = v.z; w[4*t+3] = v.w;
    }
}

// out_j = sum_k x[k] * w[j][k]   (x element k lives in lane k's reg)
__device__ __forceinline__ float dot1(float x, const float (&w)[64]) {
    float a0=0.f, a1=0.f, a2=0.f, a3=0.f;
#pragma unroll
    for (int k = 0; k < 64; k += 4) {
        a0 = fmaf(bcastf(x, k+0), w[k+0], a0);
        a1 = fmaf(bcastf(x, k+1), w[k+1], a1);
        a2 = fmaf(bcastf(x, k+2), w[k+2], a2);
        a3 = fmaf(bcastf(x, k+3), w[k+3], a3);
    }
    return (a0 + a1) + (a2 + a3);
}

// out_j = sum_k xs[k]*w1[j][k] + xm[k]*w2[j][k]
__device__ __forceinline__ float dot2(float xs, float xm,
                                      const float (&w1)[64], const float (&w2)[64]) {
    float a0=0.f, a1=0.f, a2=0.f, a3=0.f;
#pragma unroll
    for (int k = 0; k < 64; k += 2) {
        float s0 = bcastf(xs, k+0), m0 = bcastf(xm, k+0);
        float s1 = bcastf(xs, k+1), m1 = bcastf(xm, k+1);
        a0 = fmaf(s0, w1[k+0], a0);
        a1 = fmaf(m0, w2[k+0], a1);
        a2 = fmaf(s1, w1[k+1], a2);
        a3 = fmaf(m1, w2[k+1], a3);
    }
    return (a0 + a1) + (a2 + a3);
}

// ---- dsd stage 1: emb_s1[b,h1,:] = leaky((A+es)@W21^T + (A*es)@W22^T) ----
// rows = B*H1 = 8192; 1024 waves x 8 rows
__global__ __launch_bounds__(256) void k_dsd1(
    const float* __restrict__ E_s, const float* __restrict__ E_d,
    const float* __restrict__ W21, const float* __restrict__ W22,
    const int* __restrict__ dsd_1, const int* __restrict__ dsd_2,
    float* __restrict__ emb_s1)
{
    const int lane = threadIdx.x & 63;
    const int wid  = rfl((int)((blockIdx.x * blockDim.x + threadIdx.x) >> 6)); // 0..1023
    float w1[64], w2[64];
    load_wrow(w1, W21, lane);
    load_wrow(w2, W22, lane);
    for (int r = 0; r < 8; ++r) {
        int row = wid * 8 + r;                    // (b,h1)
        int is  = dsd_1[row];
        float es = E_s[(size_t)is * 64 + lane];
        const int* d2 = dsd_2 + (size_t)row * 8;
        float sA = 0.f; int cnt = 0;
#pragma unroll
        for (int h2 = 0; h2 < 8; ++h2) {
            int id = d2[h2];
            cnt += (id != 0);
            sA += E_d[(size_t)id * 64 + lane];    // E_d[0] == 0, safe to always add
        }
        float wgt = cnt > 0 ? 1.f / ((float)cnt + 1e-8f) : 0.f;
        float A = sA * wgt;
        emb_s1[(size_t)row * 64 + lane] = leakyf(dot2(A + es, A * es, w1, w2));
    }
}

// ---- dsd stage 2: emb_dise[b,:] = leaky((A3+td)@W11^T + (A3*td)@W12^T) ----
// rows = B = 1024; 256 waves x 4 rows
__global__ __launch_bounds__(256) void k_dsd2(
    const float* __restrict__ E_d,
    const float* __restrict__ W11, const float* __restrict__ W12,
    const int* __restrict__ label, const int* __restrict__ dsd_1,
    const float* __restrict__ emb_s1, float* __restrict__ emb_dise)
{
    const int lane = threadIdx.x & 63;
    const int wid  = rfl((int)((blockIdx.x * blockDim.x + threadIdx.x) >> 6)); // 0..255
    float w1[64], w2[64];
    load_wrow(w1, W11, lane);
    load_wrow(w2, W12, lane);
    for (int r = 0; r < 4; ++r) {
        int b = wid * 4 + r;
        float sE = 0.f; int cnt = 0;
#pragma unroll
        for (int h1 = 0; h1 < 8; ++h1) {
            sE  += emb_s1[(size_t)(b * 8 + h1) * 64 + lane];
            cnt += (dsd_1[b * 8 + h1] != 0);
        }
        float wgt = cnt > 0 ? 1.f / ((float)cnt + 1e-8f) : 0.f;
        float A3 = sE * wgt;
        float td = E_d[(size_t)label[b] * 64 + lane];
        emb_dise[(size_t)b * 64 + lane] = leakyf(dot2(A3 + td, A3 * td, w1, w2));
    }
}

// ---- usu stages 1+2 fused per (b,u1): es1[p,:] ----
// p = B*U1 = 8192; 2048 waves x 4 p. Per p: 8 u2-rows (avg 16 E_s rows, W3
// matmul, leaky, accumulate), then pair matmul W21u/W22u.
__global__ __launch_bounds__(256) void k_usu(
    const float* __restrict__ E_s,
    const float* __restrict__ W3, const float* __restrict__ W21u, const float* __restrict__ W22u,
    const int* __restrict__ usu_1, const int* __restrict__ usu_2, const int* __restrict__ usu_3,
    float* __restrict__ es1)
{
    const int lane = threadIdx.x & 63;
    const int wid  = rfl((int)((blockIdx.x * blockDim.x + threadIdx.x) >> 6)); // 0..2047
    float w3[64], w1[64], w2[64];
    load_wrow(w3, W3,   lane);
    load_wrow(w1, W21u, lane);
    load_wrow(w2, W22u, lane);
    for (int r = 0; r < 4; ++r) {
        int p = wid * 4 + r;                      // (b,u1)
        float sE = 0.f;
        for (int u2 = 0; u2 < 8; ++u2) {
            const int* i3 = usu_3 + ((size_t)p * 8 + u2) * 16;
            float sS = 0.f; int cnt = 0;
#pragma unroll
            for (int t = 0; t < 16; ++t) {
                int id = i3[t];
                cnt += (id != 0);
                sS += E_s[(size_t)id * 64 + lane]; // E_s[0] == 0
            }
            float wgt = cnt > 0 ? 1.f / ((float)cnt + 1e-8f) : 0.f;
            sE += leakyf(dot1(sS * wgt, w3));     // eu2 row, summed over u2
        }
        int cnt2 = 0;
        const int* m2 = usu_2 + (size_t)p * 8;
#pragma unroll
        for (int u2 = 0; u2 < 8; ++u2) cnt2 += (m2[u2] != 0);
        float wgt2 = cnt2 > 0 ? 1.f / ((float)cnt2 + 1e-8f) : 0.f;
        float A2 = sE * wgt2;
        float u1e = E_s[(size_t)usu_1[p] * 64 + lane];
        es1[(size_t)p * 64 + lane] = leakyf(dot2(A2 + u1e, A2 * u1e, w1, w2));
    }
}

// ---- usu final + dot with emb_dise ----
// rows = B = 1024; 256 waves x 4 rows
__global__ __launch_bounds__(256) void k_fin(
    const float* __restrict__ W1u, const int* __restrict__ usu_1,
    const float* __restrict__ es1, const float* __restrict__ emb_dise,
    float* __restrict__ out)
{
    const int lane = threadIdx.x & 63;
    const int wid  = rfl((int)((blockIdx.x * blockDim.x + threadIdx.x) >> 6)); // 0..255
    float w1[64];
    load_wrow(w1, W1u, lane);
    for (int r = 0; r < 4; ++r) {
        int b = wid * 4 + r;
        float sE = 0.f; int cnt = 0;
#pragma unroll
        for (int u1 = 0; u1 < 8; ++u1) {
            sE  += es1[(size_t)(b * 8 + u1) * 64 + lane];
            cnt += (usu_1[b * 8 + u1] != 0);
        }
        float wgt = cnt > 0 ? 1.f / ((float)cnt + 1e-8f) : 0.f;
        float eu = leakyf(dot1(sE * wgt, w1));    // emb_user element
        float pr = eu * emb_dise[(size_t)b * 64 + lane];
#pragma unroll
        for (int off = 32; off > 0; off >>= 1) pr += __shfl_down(pr, off, 64);
        if (lane == 0) out[b] = pr;
    }
}

extern "C" void kernel_launch(void* const* d_in, const int* in_sizes, int n_in,
                              void* d_out, int out_size, void* d_ws, size_t ws_size,
                              hipStream_t stream) {
    const float* E_s  = (const float*)d_in[0];
    const float* E_d  = (const float*)d_in[1];
    const float* W_dsd_21 = (const float*)d_in[2];
    const float* W_dsd_22 = (const float*)d_in[3];
    const float* W_dsd_11 = (const float*)d_in[4];
    const float* W_dsd_12 = (const float*)d_in[5];
    const float* W_usu_3  = (const float*)d_in[6];
    const float* W_usu_21 = (const float*)d_in[7];
    const float* W_usu_22 = (const float*)d_in[8];
    const float* W_usu_1  = (const float*)d_in[9];
    const int* label = (const int*)d_in[10];
    const int* dsd_1 = (const int*)d_in[11];
    const int* dsd_2 = (const int*)d_in[12];
    const int* usu_1 = (const int*)d_in[13];
    const int* usu_2 = (const int*)d_in[14];
    const int* usu_3 = (const int*)d_in[15];
    float* out = (float*)d_out;

    // scratch layout (all fp32): emb_s1 [8192*64], emb_dise [1024*64], es1 [8192*64]
    float* emb_s1   = (float*)d_ws;
    float* emb_dise = emb_s1 + 8192 * 64;
    float* es1      = emb_dise + 1024 * 64;

    k_dsd1<<<256, 256, 0, stream>>>(E_s, E_d, W_dsd_21, W_dsd_22, dsd_1, dsd_2, emb_s1);
    k_dsd2<<<64, 256, 0, stream>>>(E_d, W_dsd_11, W_dsd_12, label, dsd_1, emb_s1, emb_dise);
    k_usu<<<512, 256, 0, stream>>>(E_s, W_usu_3, W_usu_21, W_usu_22, usu_1, usu_2, usu_3, es1);
    k_fin<<<64, 256, 0, stream>>>(W_usu_1, usu_1, es1, emb_dise, out);
}